// Round 1
// baseline (9096.931 us; speedup 1.0000x reference)
//
#include <hip/hip_runtime.h>

#define N_IN_SZ   400000
#define N_OUT_SZ  200000
#define K_OFF     27
#define R_RULES   200000
#define NC        32          // channels in == channels out

// ---------------------------------------------------------------------------
// init: out[o][c] = bias[c]   (d_out is poisoned 0xAA; must rewrite each call)
// ---------------------------------------------------------------------------
__global__ __launch_bounds__(256) void init_out_kernel(
    const float* __restrict__ bias, float* __restrict__ out)
{
    int idx = blockIdx.x * 256 + threadIdx.x;          // float4 index
    const int total4 = N_OUT_SZ * NC / 4;
    if (idx >= total4) return;
    int c0 = (idx * 4) & (NC - 1);
    float4 b;
    b.x = bias[c0 + 0];
    b.y = bias[c0 + 1];
    b.z = bias[c0 + 2];
    b.w = bias[c0 + 3];
    reinterpret_cast<float4*>(out)[idx] = b;
}

// ---------------------------------------------------------------------------
// conv: one thread per rule. Stage W[k] (32x32 f32 = 4KB) in LDS; broadcast
// reads (all lanes same address) are bank-conflict-free. 32 atomicAdd per rule.
// ---------------------------------------------------------------------------
__global__ __launch_bounds__(256) void conv_scatter_kernel(
    const float* __restrict__ feat,     // [N_IN, 32]
    const float* __restrict__ weight,   // [27*32, 32]
    const int*   __restrict__ in_idx,   // [27, R]
    const int*   __restrict__ out_idx,  // [27, R]
    float*       __restrict__ out)      // [N_OUT, 32]
{
    __shared__ float Wlds[NC * NC];

    const int k = blockIdx.y;

    // cooperative load of W[k] into LDS: weight[(k*32 + i)*32 + c]
    for (int t = threadIdx.x; t < NC * NC; t += 256)
        Wlds[t] = weight[k * NC * NC + t];
    __syncthreads();

    const int r = blockIdx.x * 256 + threadIdx.x;
    if (r >= R_RULES) return;

    const int irow = in_idx[k * R_RULES + r];
    const int orow = out_idx[k * R_RULES + r];

    // load input row: 32 contiguous f32 = 8 x float4 (128B burst per lane)
    const float4* fv = reinterpret_cast<const float4*>(feat + (size_t)irow * NC);
    float4 f[8];
#pragma unroll
    for (int i = 0; i < 8; ++i) f[i] = fv[i];

    float acc[NC];
#pragma unroll
    for (int c = 0; c < NC; ++c) acc[c] = 0.0f;

#pragma unroll
    for (int i0 = 0; i0 < 8; ++i0) {
        const float fe0 = f[i0].x, fe1 = f[i0].y, fe2 = f[i0].z, fe3 = f[i0].w;
        const int i = i0 * 4;
#pragma unroll
        for (int c = 0; c < NC; ++c) {
            // uniform LDS addresses across lanes -> broadcast, conflict-free;
            // consecutive c -> compiler can fuse into ds_read_b128
            acc[c] += fe0 * Wlds[(i + 0) * NC + c];
            acc[c] += fe1 * Wlds[(i + 1) * NC + c];
            acc[c] += fe2 * Wlds[(i + 2) * NC + c];
            acc[c] += fe3 * Wlds[(i + 3) * NC + c];
        }
    }

    float* op = out + (size_t)orow * NC;
#pragma unroll
    for (int c = 0; c < NC; ++c)
        atomicAdd(op + c, acc[c]);
}

// ---------------------------------------------------------------------------
extern "C" void kernel_launch(void* const* d_in, const int* in_sizes, int n_in,
                              void* d_out, int out_size, void* d_ws, size_t ws_size,
                              hipStream_t stream)
{
    const float* feat    = (const float*)d_in[0];
    const float* weight  = (const float*)d_in[1];
    const float* bias    = (const float*)d_in[2];
    const int*   in_idx  = (const int*)d_in[3];
    const int*   out_idx = (const int*)d_in[4];
    float*       out     = (float*)d_out;

    // 1) out = bias (overwrites poison every call)
    {
        int total4 = N_OUT_SZ * NC / 4;
        int blocks = (total4 + 255) / 256;
        init_out_kernel<<<blocks, 256, 0, stream>>>(bias, out);
    }

    // 2) scatter-add convolution
    {
        dim3 grid((R_RULES + 255) / 256, K_OFF);
        conv_scatter_kernel<<<grid, 256, 0, stream>>>(feat, weight, in_idx, out_idx, out);
    }
}

// Round 2
// 729.511 us; speedup vs baseline: 12.4699x; 12.4699x over previous
//
#include <hip/hip_runtime.h>

#define N_IN_SZ   400000
#define N_OUT_SZ  200000
#define K_OFF     27
#define R_RULES   200000
#define NC        32          // channels in == channels out
#define RPB       64          // rules per block (per k-offset)

// ---------------------------------------------------------------------------
// init: out[o][c] = bias[c]   (d_out is poisoned 0xAA; must rewrite each call)
// ---------------------------------------------------------------------------
__global__ __launch_bounds__(256) void init_out_kernel(
    const float* __restrict__ bias, float* __restrict__ out)
{
    int idx = blockIdx.x * 256 + threadIdx.x;          // float4 index
    const int total4 = N_OUT_SZ * NC / 4;
    if (idx >= total4) return;
    int c0 = (idx * 4) & (NC - 1);
    float4 b;
    b.x = bias[c0 + 0];
    b.y = bias[c0 + 1];
    b.z = bias[c0 + 2];
    b.w = bias[c0 + 3];
    reinterpret_cast<float4*>(out)[idx] = b;
}

// ---------------------------------------------------------------------------
// conv: channel = lane. A 32-lane group owns one rule at a time; lane c
// computes out[orow][c] += dot(feat[irow][:], W[k][:][c]).
// W column c lives in 32 registers (loaded once per block). The 32 atomics
// of a rule are lane-consecutive -> one contiguous 128B region per group.
// ---------------------------------------------------------------------------
__global__ __launch_bounds__(256) void conv_scatter_kernel(
    const float* __restrict__ feat,     // [N_IN, 32]
    const float* __restrict__ weight,   // [27*32, 32]
    const int*   __restrict__ in_idx,   // [27, R]
    const int*   __restrict__ out_idx,  // [27, R]
    float*       __restrict__ out)      // [N_OUT, 32]
{
    __shared__ float Wlds[NC * NC];

    const int k  = blockIdx.y;
    const int c  = threadIdx.x & (NC - 1);   // channel = lane within group
    const int rg = threadIdx.x >> 5;         // rule-group id within block (0..7)

    // cooperative load of W[k] into LDS: Wlds[i*32 + c] = W[k][i][c]
    for (int t = threadIdx.x; t < NC * NC; t += 256)
        Wlds[t] = weight[k * NC * NC + t];
    __syncthreads();

    // hoist weight column c into registers (stride-1 across lanes: conflict-free)
    float wcol[NC];
#pragma unroll
    for (int i = 0; i < NC; ++i)
        wcol[i] = Wlds[i * NC + c];

    const int rbase = blockIdx.x * RPB;

    for (int rr = rg; rr < RPB; rr += 8) {
        const int r = rbase + rr;
        // broadcast loads (all 32 lanes of the group read the same address)
        const int irow = in_idx[k * R_RULES + r];
        const int orow = out_idx[k * R_RULES + r];

        const float4* fv = reinterpret_cast<const float4*>(feat + (size_t)irow * NC);

        float acc = 0.0f;
#pragma unroll
        for (int i0 = 0; i0 < 8; ++i0) {
            const float4 f = fv[i0];           // broadcast within group
            acc += f.x * wcol[i0 * 4 + 0];
            acc += f.y * wcol[i0 * 4 + 1];
            acc += f.z * wcol[i0 * 4 + 2];
            acc += f.w * wcol[i0 * 4 + 3];
        }

        // lanes 0..31 of the group hit 32 consecutive floats = 128B contiguous
        atomicAdd(out + (size_t)orow * NC + c, acc);
    }
}

// ---------------------------------------------------------------------------
extern "C" void kernel_launch(void* const* d_in, const int* in_sizes, int n_in,
                              void* d_out, int out_size, void* d_ws, size_t ws_size,
                              hipStream_t stream)
{
    const float* feat    = (const float*)d_in[0];
    const float* weight  = (const float*)d_in[1];
    const float* bias    = (const float*)d_in[2];
    const int*   in_idx  = (const int*)d_in[3];
    const int*   out_idx = (const int*)d_in[4];
    float*       out     = (float*)d_out;

    // 1) out = bias (overwrites poison every call)
    {
        int total4 = N_OUT_SZ * NC / 4;
        int blocks = (total4 + 255) / 256;
        init_out_kernel<<<blocks, 256, 0, stream>>>(bias, out);
    }

    // 2) scatter-add convolution, channel-per-lane layout
    {
        dim3 grid(R_RULES / RPB, K_OFF);   // 200000/64 = 3125 exactly
        conv_scatter_kernel<<<grid, 256, 0, stream>>>(feat, weight, in_idx, out_idx, out);
    }
}